// Round 2
// baseline (266.120 us; speedup 1.0000x reference)
//
#include <hip/hip_runtime.h>
#include <math.h>

// Problem constants (from reference): N=65536 rows, D=512 features, K=5 centroids.
#define LFR_N 65536
#define LFR_D 512
#define LFR_K 5
#define ROWS  4   // rows processed concurrently per wave iteration (ILP)

// One wave (64 lanes) per ROWS rows; lane owns 8 contiguous d's -> float4 x2
// coalesced per row. ROWS=4 keeps 8 loads in flight and gives the 6-step
// shuffle butterfly 20 independent swizzles per step (latency amortized 4x).
// R0 post-mortem: 1-row/iter version was chain-latency-bound at 2.4 TB/s.
__global__ __launch_bounds__(256) void lfr_kernel(
    const float* __restrict__ x,        // (N, D)
    const float* __restrict__ alpha,    // (D,)
    const float* __restrict__ w,        // (K, 1)
    const float* __restrict__ cent,     // (K, D)
    float* __restrict__ out_map,        // (N, K)
    float* __restrict__ out_rec,        // (N, D)
    float* __restrict__ out_pred)       // (N,)
{
    const int lane           = threadIdx.x & 63;
    const int wave_in_block  = threadIdx.x >> 6;
    const int waves_per_blk  = blockDim.x >> 6;
    const int wave_id        = blockIdx.x * waves_per_blk + wave_in_block;
    const int num_waves      = gridDim.x * waves_per_blk;

    const int d0 = lane * 8;  // this lane's 8 feature indices

    // ---- per-lane constants (L2-hit loads, once per wave) ----
    float al[8];
    {
        float4 a0 = *(const float4*)(alpha + d0);
        float4 a1 = *(const float4*)(alpha + d0 + 4);
        al[0]=a0.x; al[1]=a0.y; al[2]=a0.z; al[3]=a0.w;
        al[4]=a1.x; al[5]=a1.y; al[6]=a1.z; al[7]=a1.w;
    }
    float c[LFR_K][8];
    #pragma unroll
    for (int k = 0; k < LFR_K; ++k) {
        float4 c0 = *(const float4*)(cent + k * LFR_D + d0);
        float4 c1 = *(const float4*)(cent + k * LFR_D + d0 + 4);
        c[k][0]=c0.x; c[k][1]=c0.y; c[k][2]=c0.z; c[k][3]=c0.w;
        c[k][4]=c1.x; c[k][5]=c1.y; c[k][6]=c1.z; c[k][7]=c1.w;
    }
    float sigw[LFR_K];
    #pragma unroll
    for (int k = 0; k < LFR_K; ++k)
        sigw[k] = 1.0f / (1.0f + __expf(-w[k]));

    for (int rb = wave_id * ROWS; rb < LFR_N; rb += num_waves * ROWS) {
        // ---- load ROWS rows' x values (all loads in flight together) ----
        float xv[ROWS][8];
        #pragma unroll
        for (int r = 0; r < ROWS; ++r) {
            const float* xr = x + (size_t)(rb + r) * LFR_D + d0;
            float4 x0 = *(const float4*)(xr);
            float4 x1 = *(const float4*)(xr + 4);
            xv[r][0]=x0.x; xv[r][1]=x0.y; xv[r][2]=x0.z; xv[r][3]=x0.w;
            xv[r][4]=x1.x; xv[r][5]=x1.y; xv[r][6]=x1.z; xv[r][7]=x1.w;
        }

        // ---- partial weighted squared distances ----
        float dist[ROWS][LFR_K];
        #pragma unroll
        for (int r = 0; r < ROWS; ++r) {
            #pragma unroll
            for (int k = 0; k < LFR_K; ++k) {
                float acc = 0.0f;
                #pragma unroll
                for (int j = 0; j < 8; ++j) {
                    float df = xv[r][j] - c[k][j];
                    acc = fmaf(al[j] * df, df, acc);
                }
                dist[r][k] = acc;
            }
        }

        // ---- wave butterfly reduction: 6 steps x (ROWS*K) independent swizzles ----
        #pragma unroll
        for (int off = 32; off > 0; off >>= 1) {
            #pragma unroll
            for (int r = 0; r < ROWS; ++r)
                #pragma unroll
                for (int k = 0; k < LFR_K; ++k)
                    dist[r][k] += __shfl_xor(dist[r][k], off);
        }

        // ---- softmax over K per row (wave-uniform, redundant per lane) ----
        float m[ROWS][LFR_K];
        #pragma unroll
        for (int r = 0; r < ROWS; ++r) {
            float mx = dist[r][0];
            #pragma unroll
            for (int k = 1; k < LFR_K; ++k) mx = fmaxf(mx, dist[r][k]);
            float s = 0.0f;
            #pragma unroll
            for (int k = 0; k < LFR_K; ++k) { m[r][k] = __expf(dist[r][k] - mx); s += m[r][k]; }
            float inv = 1.0f / s;
            #pragma unroll
            for (int k = 0; k < LFR_K; ++k) m[r][k] *= inv;
        }

        // ---- reconstruction: rec[d] = sum_k m[k] * c[k][d] ----
        #pragma unroll
        for (int r = 0; r < ROWS; ++r) {
            float rv[8];
            #pragma unroll
            for (int j = 0; j < 8; ++j) {
                float acc = m[r][0] * c[0][j];
                #pragma unroll
                for (int k = 1; k < LFR_K; ++k) acc = fmaf(m[r][k], c[k][j], acc);
                rv[j] = acc;
            }
            float* rr = out_rec + (size_t)(rb + r) * LFR_D + d0;
            *(float4*)(rr)     = make_float4(rv[0], rv[1], rv[2], rv[3]);
            *(float4*)(rr + 4) = make_float4(rv[4], rv[5], rv[6], rv[7]);
        }

        // ---- mapping + pred (every lane has all m values) ----
        if (lane < ROWS * LFR_K) {
            int r = lane / LFR_K, k = lane - r * LFR_K;
            out_map[(size_t)(rb + r) * LFR_K + k] = m[r][k];
        }
        if (lane >= 32 && lane < 32 + ROWS) {
            int r = lane - 32;
            float p = 0.0f;
            #pragma unroll
            for (int k = 0; k < LFR_K; ++k) p = fmaf(m[r][k], sigw[k], p);
            out_pred[rb + r] = p;
        }
    }
}

extern "C" void kernel_launch(void* const* d_in, const int* in_sizes, int n_in,
                              void* d_out, int out_size, void* d_ws, size_t ws_size,
                              hipStream_t stream) {
    const float* x     = (const float*)d_in[0];   // (N, D)
    // d_in[1] = is_protected — unused by the reference computation
    const float* alpha = (const float*)d_in[2];   // (D,)
    const float* w     = (const float*)d_in[3];   // (K, 1)
    const float* cent  = (const float*)d_in[4];   // (K, D)

    float* out   = (float*)d_out;
    float* o_map = out;                                         // N*K
    float* o_rec = out + (size_t)LFR_N * LFR_K;                 // N*D
    float* o_prd = out + (size_t)LFR_N * LFR_K + (size_t)LFR_N * LFR_D;  // N

    // 2048 blocks x 256 threads = 8192 waves x ROWS=4 -> 2 iterations per wave.
    dim3 grid(2048), block(256);
    lfr_kernel<<<grid, block, 0, stream>>>(x, alpha, w, cent, o_map, o_rec, o_prd);
}

// Round 3
// 241.864 us; speedup vs baseline: 1.1003x; 1.1003x over previous
//
#include <hip/hip_runtime.h>
#include <math.h>

// Problem constants (from reference): N=65536 rows, D=512 features, K=5 centroids.
#define LFR_N 65536
#define LFR_D 512
#define LFR_K 5
#define ROWS  4   // rows per wave (ILP); grid sized so each wave does exactly one block of ROWS rows

// One wave (64 lanes) per ROWS rows; lane owns 8 contiguous d's -> float4 x2
// coalesced per row. All private-array indexing is COMPILE-TIME CONSTANT:
// R1 post-mortem showed m[r][k] with runtime r,k demoted the array to LDS
// (LDS_Block_Size=20480 = 256thr x 20 floats) and regressed 83->102us.
__global__ __launch_bounds__(256) void lfr_kernel(
    const float* __restrict__ x,        // (N, D)
    const float* __restrict__ alpha,    // (D,)
    const float* __restrict__ w,        // (K, 1)
    const float* __restrict__ cent,     // (K, D)
    float* __restrict__ out_map,        // (N, K)
    float* __restrict__ out_rec,        // (N, D)
    float* __restrict__ out_pred)       // (N,)
{
    const int lane          = threadIdx.x & 63;
    const int wave_in_block = threadIdx.x >> 6;
    const int wave_id       = blockIdx.x * (blockDim.x >> 6) + wave_in_block;
    const int rb            = wave_id * ROWS;   // first of this wave's ROWS rows
    if (rb >= LFR_N) return;

    const int d0 = lane * 8;  // this lane's 8 feature indices

    // ---- issue all ROWS x-row loads first (independent, in flight together) ----
    float4 xl[ROWS][2];
    #pragma unroll
    for (int r = 0; r < ROWS; ++r) {
        const float* xr = x + (size_t)(rb + r) * LFR_D + d0;
        xl[r][0] = *(const float4*)(xr);
        xl[r][1] = *(const float4*)(xr + 4);
    }

    // ---- per-lane constants (L1/L2-hit after first waves) ----
    float al[8];
    {
        float4 a0 = *(const float4*)(alpha + d0);
        float4 a1 = *(const float4*)(alpha + d0 + 4);
        al[0]=a0.x; al[1]=a0.y; al[2]=a0.z; al[3]=a0.w;
        al[4]=a1.x; al[5]=a1.y; al[6]=a1.z; al[7]=a1.w;
    }
    float c[LFR_K][8];
    #pragma unroll
    for (int k = 0; k < LFR_K; ++k) {
        float4 c0 = *(const float4*)(cent + k * LFR_D + d0);
        float4 c1 = *(const float4*)(cent + k * LFR_D + d0 + 4);
        c[k][0]=c0.x; c[k][1]=c0.y; c[k][2]=c0.z; c[k][3]=c0.w;
        c[k][4]=c1.x; c[k][5]=c1.y; c[k][6]=c1.z; c[k][7]=c1.w;
    }
    float sigw[LFR_K];
    #pragma unroll
    for (int k = 0; k < LFR_K; ++k)
        sigw[k] = 1.0f / (1.0f + __expf(-w[k]));

    // ---- partial weighted squared distances ----
    float xv[ROWS][8];
    #pragma unroll
    for (int r = 0; r < ROWS; ++r) {
        xv[r][0]=xl[r][0].x; xv[r][1]=xl[r][0].y; xv[r][2]=xl[r][0].z; xv[r][3]=xl[r][0].w;
        xv[r][4]=xl[r][1].x; xv[r][5]=xl[r][1].y; xv[r][6]=xl[r][1].z; xv[r][7]=xl[r][1].w;
    }
    float dist[ROWS][LFR_K];
    #pragma unroll
    for (int r = 0; r < ROWS; ++r) {
        #pragma unroll
        for (int k = 0; k < LFR_K; ++k) {
            float acc = 0.0f;
            #pragma unroll
            for (int j = 0; j < 8; ++j) {
                float df = xv[r][j] - c[k][j];
                acc = fmaf(al[j] * df, df, acc);
            }
            dist[r][k] = acc;
        }
    }

    // ---- wave butterfly reduction: 6 steps x (ROWS*K)=20 independent swizzles ----
    #pragma unroll
    for (int off = 32; off > 0; off >>= 1) {
        #pragma unroll
        for (int r = 0; r < ROWS; ++r)
            #pragma unroll
            for (int k = 0; k < LFR_K; ++k)
                dist[r][k] += __shfl_xor(dist[r][k], off);
    }

    // ---- softmax over K per row (wave-uniform, redundant per lane) ----
    float m[ROWS][LFR_K];
    #pragma unroll
    for (int r = 0; r < ROWS; ++r) {
        float mx = dist[r][0];
        #pragma unroll
        for (int k = 1; k < LFR_K; ++k) mx = fmaxf(mx, dist[r][k]);
        float s = 0.0f;
        #pragma unroll
        for (int k = 0; k < LFR_K; ++k) { m[r][k] = __expf(dist[r][k] - mx); s += m[r][k]; }
        float inv = 1.0f / s;
        #pragma unroll
        for (int k = 0; k < LFR_K; ++k) m[r][k] *= inv;
    }

    // ---- reconstruction: rec[d] = sum_k m[k] * c[k][d] ----
    #pragma unroll
    for (int r = 0; r < ROWS; ++r) {
        float rv[8];
        #pragma unroll
        for (int j = 0; j < 8; ++j) {
            float acc = m[r][0] * c[0][j];
            #pragma unroll
            for (int k = 1; k < LFR_K; ++k) acc = fmaf(m[r][k], c[k][j], acc);
            rv[j] = acc;
        }
        float* rr = out_rec + (size_t)(rb + r) * LFR_D + d0;
        *(float4*)(rr)     = make_float4(rv[0], rv[1], rv[2], rv[3]);
        *(float4*)(rr + 4) = make_float4(rv[4], rv[5], rv[6], rv[7]);
    }

    // ---- mapping + pred: lane r writes row r, ALL indices compile-time ----
    #pragma unroll
    for (int r = 0; r < ROWS; ++r) {
        if (lane == r) {
            float* mp = out_map + (size_t)(rb + r) * LFR_K;
            *(float4*)(mp) = make_float4(m[r][0], m[r][1], m[r][2], m[r][3]);
            mp[4] = m[r][4];
            float p = m[r][0] * sigw[0];
            #pragma unroll
            for (int k = 1; k < LFR_K; ++k) p = fmaf(m[r][k], sigw[k], p);
            out_pred[rb + r] = p;
        }
    }
}

extern "C" void kernel_launch(void* const* d_in, const int* in_sizes, int n_in,
                              void* d_out, int out_size, void* d_ws, size_t ws_size,
                              hipStream_t stream) {
    const float* x     = (const float*)d_in[0];   // (N, D)
    // d_in[1] = is_protected — unused by the reference computation
    const float* alpha = (const float*)d_in[2];   // (D,)
    const float* w     = (const float*)d_in[3];   // (K, 1)
    const float* cent  = (const float*)d_in[4];   // (K, D)

    float* out   = (float*)d_out;
    float* o_map = out;                                         // N*K
    float* o_rec = out + (size_t)LFR_N * LFR_K;                 // N*D
    float* o_prd = out + (size_t)LFR_N * LFR_K + (size_t)LFR_N * LFR_D;  // N

    // 4096 blocks x 256 threads = 16384 waves x ROWS=4 rows = 65536 rows,
    // exactly one row-block per wave (max TLP, no grid-stride loop).
    dim3 grid(LFR_N / (4 * ROWS)), block(256);
    lfr_kernel<<<grid, block, 0, stream>>>(x, alpha, w, cent, o_map, o_rec, o_prd);
}